// Round 3
// baseline (1833.076 us; speedup 1.0000x reference)
//
#include <hip/hip_runtime.h>
#include <stdint.h>

typedef unsigned short ushortT;
typedef __attribute__((ext_vector_type(8))) short short8;     // 8 x bf16 (MFMA frag)
typedef __attribute__((ext_vector_type(4))) float float4v;
typedef __attribute__((ext_vector_type(4))) int int4v;
typedef __attribute__((ext_vector_type(2))) int int2v;
typedef __attribute__((ext_vector_type(4))) unsigned short ushort4v;

// ---- workspace layout (bytes) ----
#define OFF_HDR      0            // int[3]: K, maxlen, mask_mode
#define OFF_LEN      8192         // int[256]
#define OFF_CUMM     12288        // int[512]
#define OFF_CUMP     16384        // int[512]
#define OFF_MTI      32768        // int[131072]  maskTrueIdx
#define OFF_PARR     557056       // int[131072]  p_array (packed rank or -1)
#define OFF_WIH      1605632      // bf16[768*256]
#define OFF_WHH      1998848      // bf16[768*256]
#define OFF_GI       2392064      // bf16[131072*768] input projections (packed order)

#define HLAST_OFF    33554432     // floats: T*B*H

__device__ __forceinline__ ushortT f2bf(float f) {
  unsigned u = __float_as_uint(f);
  unsigned r = (u + 0x7fffu + ((u >> 16) & 1u)) >> 16;
  return (ushortT)r;
}
__device__ __forceinline__ float bf2f(ushortT h) {
  return __uint_as_float(((unsigned)h) << 16);
}
__device__ __forceinline__ float sigf(float x) { return 1.f / (1.f + __expf(-x)); }
__device__ __forceinline__ float tanhfast(float x) { return 1.f - 2.f / (1.f + __expf(2.f * x)); }

// barrier with LDS visibility only: leaves vmem (global loads/stores) in flight
__device__ __forceinline__ void bar_lds() {
  asm volatile("s_waitcnt lgkmcnt(0)\n\ts_barrier" ::: "memory");
}

// ---------------- k_prep: lengths, row/col sums, scans, mask dtype detect ----------------
__global__ __launch_bounds__(512) void k_prep(const int* __restrict__ mask, int* __restrict__ wsi) {
  __shared__ int m_s[512], colp[512], len_s[256], sA[512], sB[512];
  __shared__ int sh_mode;
  const int tid = threadIdx.x;
  if (tid == 0) sh_mode = 0;
  __syncthreads();
  int bad = 0;
  for (int i = tid; i < 32768; i += 512) {
    unsigned v = ((const unsigned*)mask)[i];
    if (v > 1u) bad = 1;
  }
  if (bad) atomicOr(&sh_mode, 1);
  __syncthreads();
  const int mode = sh_mode;

  int s = 0;
  if (mode) {
    const unsigned char* mb = (const unsigned char*)mask;
    for (int c = 0; c < 256; c += 4) {
      unsigned v = *(const unsigned*)(mb + tid * 256 + c);
      s += (v & 0xff) + ((v >> 8) & 0xff) + ((v >> 16) & 0xff) + ((v >> 24) & 0xff);
    }
  } else {
    const int4v* mr = (const int4v*)(mask + tid * 256);
    for (int c = 0; c < 64; ++c) { int4v v = mr[c]; s += v[0] + v[1] + v[2] + v[3]; }
  }
  m_s[tid] = s;

  const int b = tid & 255, hh = tid >> 8;
  int cs = 0;
  if (mode) {
    const unsigned char* mb = (const unsigned char*)mask;
    for (int r = hh * 256; r < hh * 256 + 256; ++r) cs += mb[r * 256 + b];
  } else {
    for (int r = hh * 256; r < hh * 256 + 256; ++r) cs += mask[r * 256 + b];
  }
  colp[tid] = cs;
  __syncthreads();
  if (tid < 256) len_s[tid] = colp[tid] + colp[tid + 256];
  __syncthreads();

  int nt = 0;
  for (int i = 0; i < 256; ++i) nt += (len_s[i] > tid) ? 1 : 0;

  sA[tid] = m_s[tid]; sB[tid] = nt;
  for (int off = 1; off < 512; off <<= 1) {
    __syncthreads();
    int am = (tid >= off) ? sA[tid - off] : 0;
    int an = (tid >= off) ? sB[tid - off] : 0;
    __syncthreads();
    sA[tid] += am; sB[tid] += an;
  }
  __syncthreads();
  wsi[OFF_CUMM / 4 + tid] = sA[tid] - m_s[tid];
  wsi[OFF_CUMP / 4 + tid] = sB[tid] - nt;
  if (tid < 256) wsi[OFF_LEN / 4 + tid] = len_s[tid];

  colp[tid] = (tid < 256) ? len_s[tid] : 0;
  for (int off = 256; off >= 1; off >>= 1) {
    __syncthreads();
    int o = (tid < off) ? colp[tid + off] : 0;
    __syncthreads();
    if (tid < off) colp[tid] = max(colp[tid], o);
  }
  __syncthreads();
  if (tid == 0) { wsi[0] = sA[511]; wsi[1] = colp[0]; wsi[2] = mode; }
}

// ---------------- k_build: per-row scans -> maskTrueIdx and p_array ----------------
__global__ __launch_bounds__(256) void k_build(const int* __restrict__ mask, int* __restrict__ wsi) {
  const int t = blockIdx.x, b = threadIdx.x;
  const int mode = wsi[2];
  const int lane = b & 63, wv = b >> 6;
  int mflag = mode ? (int)((const unsigned char*)mask)[t * 256 + b] : mask[t * 256 + b];
  mflag = mflag ? 1 : 0;
  const int len = wsi[OFF_LEN / 4 + b];
  const int pflag = (t < len) ? 1 : 0;
  unsigned long long bm = __ballot(mflag), bp = __ballot(pflag);
  __shared__ int wm[4], wp[4];
  if (lane == 0) { wm[wv] = __popcll(bm); wp[wv] = __popcll(bp); }
  __syncthreads();
  int baseM = 0, baseP = 0;
  for (int i = 0; i < wv; ++i) { baseM += wm[i]; baseP += wp[i]; }
  unsigned long long lt = (1ull << lane) - 1ull;
  const int moff = baseM + __popcll(bm & lt);
  const int poff = baseP + __popcll(bp & lt);
  const int j = t * 256 + b;
  if (mflag) wsi[OFF_MTI / 4 + wsi[OFF_CUMM / 4 + t] + moff] = j;
  wsi[OFF_PARR / 4 + j] = pflag ? (wsi[OFF_CUMP / 4 + t] + poff) : -1;
}

// ---------------- k_wcvt: W_ih, W_hh fp32 -> bf16 ----------------
__global__ __launch_bounds__(256) void k_wcvt(const float* __restrict__ Wih,
                                              const float* __restrict__ Whh,
                                              int* __restrict__ wsi) {
  const int idx = (blockIdx.x * 256 + threadIdx.x) * 4;
  const float* src;
  ushortT* dst;
  if (idx < 196608) { src = Wih + idx; dst = (ushortT*)((char*)wsi + OFF_WIH) + idx; }
  else { src = Whh + (idx - 196608); dst = (ushortT*)((char*)wsi + OFF_WHH) + (idx - 196608); }
  float4v v = *(const float4v*)src;
  ushort4v o;
  o[0] = f2bf(v[0]); o[1] = f2bf(v[1]); o[2] = f2bf(v[2]); o[3] = f2bf(v[3]);
  *(ushort4v*)dst = o;
}

// ---------------- k_gemm: gi[p] = bf16( x[mti[p]] @ W_ih^T )  (gather fused) ----------------
__global__ __launch_bounds__(256, 2) void k_gemm(const float* __restrict__ x, int* __restrict__ wsi) {
  const int K = wsi[0];
  const int m0 = blockIdx.x * 128;
  if (m0 >= K) return;
  const int n0 = blockIdx.y * 128;
  char* wsc = (char*)wsi;
  const ushortT* Bw = (const ushortT*)(wsc + OFF_WIH);
  ushortT* C = (ushortT*)(wsc + OFF_GI);
  __shared__ ushortT As[128 * 72], Bs[128 * 72];
  __shared__ int mti_s[128];
  const int tid = threadIdx.x, w = tid >> 6, lane = tid & 63;
  const int l15 = lane & 15, quad = lane >> 4;
  if (tid < 128) {
    int m = m0 + tid;
    mti_s[tid] = (m < K) ? wsi[OFF_MTI / 4 + m] : 0;
  }
  float4v acc[4][4];
#pragma unroll
  for (int i = 0; i < 4; ++i)
#pragma unroll
    for (int j = 0; j < 4; ++j) acc[i][j] = (float4v){0.f, 0.f, 0.f, 0.f};

  for (int k0 = 0; k0 < 256; k0 += 64) {
    __syncthreads();
#pragma unroll
    for (int i = 0; i < 8; ++i) {          // A: gather 128 rows x 64 k (fp32 -> bf16)
      int cid = i * 256 + tid;
      int row = cid >> 4, c4 = cid & 15;
      float4v v = *(const float4v*)(x + (size_t)mti_s[row] * 256 + k0 + c4 * 4);
      ushort4v o;
      o[0] = f2bf(v[0]); o[1] = f2bf(v[1]); o[2] = f2bf(v[2]); o[3] = f2bf(v[3]);
      *(ushort4v*)(As + row * 72 + c4 * 4) = o;
    }
#pragma unroll
    for (int i = 0; i < 4; ++i) {          // B: W_ih bf16
      int cid = i * 256 + tid;
      int row = cid >> 3, c8 = cid & 7;
      int4v vb = *(const int4v*)(Bw + (size_t)(n0 + row) * 256 + k0 + c8 * 8);
      *(int4v*)(Bs + row * 72 + c8 * 8) = vb;
    }
    __syncthreads();
#pragma unroll
    for (int kk = 0; kk < 2; ++kk) {
      short8 af[4], bfr[4];
#pragma unroll
      for (int i = 0; i < 4; ++i)
        af[i] = *(const short8*)(As + ((w >> 1) * 64 + i * 16 + l15) * 72 + kk * 32 + quad * 8);
#pragma unroll
      for (int j = 0; j < 4; ++j)
        bfr[j] = *(const short8*)(Bs + ((w & 1) * 64 + j * 16 + l15) * 72 + kk * 32 + quad * 8);
#pragma unroll
      for (int i = 0; i < 4; ++i)
#pragma unroll
        for (int j = 0; j < 4; ++j)
          acc[i][j] = __builtin_amdgcn_mfma_f32_16x16x32_bf16(af[i], bfr[j], acc[i][j], 0, 0, 0);
    }
  }
#pragma unroll
  for (int i = 0; i < 4; ++i) {
    int m = m0 + (w >> 1) * 64 + i * 16 + quad * 4;
#pragma unroll
    for (int j = 0; j < 4; ++j) {
      int n = n0 + (w & 1) * 64 + j * 16 + l15;
#pragma unroll
      for (int r = 0; r < 4; ++r)
        if (m + r < K) C[(size_t)(m + r) * 768 + n] = f2bf(acc[i][j][r]);
    }
  }
}

// ---------------- k_rec: per-block-independent GRU recurrence ----------------
// 16 blocks x 512 threads; block = 16 batches x full H=256. W_hh in regs.
// Raw lgkm-only barriers: gi prefetch loads and out stores stay in flight
// across the barrier (no vmcnt(0) drain).
__global__ __launch_bounds__(512, 2) void k_rec(const float* __restrict__ bih,
                                                const float* __restrict__ bhh,
                                                const float* __restrict__ h0,
                                                int* __restrict__ wsi,
                                                float* __restrict__ out) {
  const int b0 = blockIdx.x * 16;
  const int tid = threadIdx.x;
  const int w = tid >> 6, lane = tid & 63, l15 = lane & 15, quad = lane >> 4;
  char* wsc = (char*)wsi;
  const ushortT* Whh = (const ushortT*)(wsc + OFF_WHH);
  const ushortT* gib = (const ushortT*)(wsc + OFF_GI);
  const int* parr = wsi + OFF_PARR / 4;
  const int* mti = wsi + OFF_MTI / 4;
  const int K = wsi[0];

  __shared__ float gh_s[16 * 772];      // stride 772 words (772%32==4): conflict-tuned
  __shared__ ushortT hbf[16 * 264];     // [batch][k] bf16
  __shared__ int len_s[16];

  if (tid < 16) len_s[tid] = wsi[OFF_LEN / 4 + b0 + tid];

  // resident W_hh fragments: wave w owns gate-rows [96w, 96w+96) = 6 tiles
  short8 wf[6][8];
#pragma unroll
  for (int tt = 0; tt < 6; ++tt) {
    int n = w * 96 + tt * 16 + l15;
#pragma unroll
    for (int kk = 0; kk < 8; ++kk)
      wf[tt][kk] = *(const short8*)(Whh + n * 256 + kk * 32 + quad * 8);
  }

  // [B]-role: batch bB = tid>>5; cols {cA..cA+3} U {cB..cB+3}, cA=(tid&31)*4
  const int bB = tid >> 5;
  const int bg = b0 + bB;
  const int cA = (tid & 31) * 4;
  const int cB = cA + 128;

  // biases in registers (r,z merged ih+hh; n split)
  float4v brA = *(const float4v*)(bih + cA)        + *(const float4v*)(bhh + cA);
  float4v brB = *(const float4v*)(bih + cB)        + *(const float4v*)(bhh + cB);
  float4v bzA = *(const float4v*)(bih + 256 + cA)  + *(const float4v*)(bhh + 256 + cA);
  float4v bzB = *(const float4v*)(bih + 256 + cB)  + *(const float4v*)(bhh + 256 + cB);
  float4v binA = *(const float4v*)(bih + 512 + cA);
  float4v binB = *(const float4v*)(bih + 512 + cB);
  float4v bhnA = *(const float4v*)(bhh + 512 + cA);
  float4v bhnB = *(const float4v*)(bhh + 512 + cB);
  const int lenB = ((const int*)((char*)wsi + OFF_LEN))[bg];

  float4v hA = *(const float4v*)(h0 + bg * 256 + cA);
  float4v hB = *(const float4v*)(h0 + bg * 256 + cB);
  {
    ushort4v p0, p1;
#pragma unroll
    for (int j = 0; j < 4; ++j) { p0[j] = f2bf(hA[j]); p1[j] = f2bf(hB[j]); }
    *(ushort4v*)(hbf + bB * 264 + cA) = p0;
    *(ushort4v*)(hbf + bB * 264 + cB) = p1;
  }
  __syncthreads();

  int tmax = 0;
#pragma unroll
  for (int i = 0; i < 16; ++i) tmax = max(tmax, len_s[i]);

  // prefetch for t=0
  int pcur = parr[bg];
  int mcur = mti[bg];
  int2v giA_r, giA_z, giA_n, giB_r, giB_z, giB_n;
  {
    const ushortT* gp = gib + (size_t)max(pcur, 0) * 768;
    giA_r = *(const int2v*)(gp + cA);       giB_r = *(const int2v*)(gp + cB);
    giA_z = *(const int2v*)(gp + 256 + cA); giB_z = *(const int2v*)(gp + 256 + cB);
    giA_n = *(const int2v*)(gp + 512 + cA); giB_n = *(const int2v*)(gp + 512 + cB);
  }

  for (int t = 0; t < tmax; ++t) {
    // prefetch step-t+1 metadata (vmem, rides across barriers)
    int pnext = -1, mnext = 0;
    if (t + 1 < 512) {
      pnext = parr[(t + 1) * 256 + bg];
      mnext = mti[(t + 1) * 256 + bg];
    }

    // [A] gh = h @ W_hh^T
    float4v acc[6];
#pragma unroll
    for (int tt = 0; tt < 6; ++tt) acc[tt] = (float4v){0.f, 0.f, 0.f, 0.f};
#pragma unroll
    for (int kk = 0; kk < 8; ++kk) {
      short8 a = *(const short8*)((const char*)hbf + l15 * 528 + kk * 64 + quad * 16);
#pragma unroll
      for (int tt = 0; tt < 6; ++tt)
        acc[tt] = __builtin_amdgcn_mfma_f32_16x16x32_bf16(a, wf[tt][kk], acc[tt], 0, 0, 0);
    }
#pragma unroll
    for (int tt = 0; tt < 6; ++tt) {
      int n = w * 96 + tt * 16 + l15;
#pragma unroll
      for (int r = 0; r < 4; ++r)
        gh_s[(quad * 4 + r) * 772 + n] = acc[tt][r];
    }
    bar_lds();

    // [B] gate nonlinearity + h update (biases & gi in regs; no LDS bias reads)
    const bool valid = (t < lenB);
    const int nflat = t * 256 + bg;
    float4v ghrA = *(const float4v*)(gh_s + bB * 772 + cA);
    float4v ghrB = *(const float4v*)(gh_s + bB * 772 + cB);
    float4v ghzA = *(const float4v*)(gh_s + bB * 772 + 256 + cA);
    float4v ghzB = *(const float4v*)(gh_s + bB * 772 + 256 + cB);
    float4v ghnA = *(const float4v*)(gh_s + bB * 772 + 512 + cA);
    float4v ghnB = *(const float4v*)(gh_s + bB * 772 + 512 + cB);
#pragma unroll
    for (int j = 0; j < 4; ++j) {
      float grA = bf2f((ushortT)(((unsigned)giA_r[j >> 1]) >> ((j & 1) * 16)));
      float gzA = bf2f((ushortT)(((unsigned)giA_z[j >> 1]) >> ((j & 1) * 16)));
      float gnA = bf2f((ushortT)(((unsigned)giA_n[j >> 1]) >> ((j & 1) * 16)));
      float rr = sigf(grA + ghrA[j] + brA[j]);
      float zz = sigf(gzA + ghzA[j] + bzA[j]);
      float nn = tanhfast(gnA + binA[j] + rr * (ghnA[j] + bhnA[j]));
      float hv = nn + zz * (hA[j] - nn);
      hA[j] = valid ? hv : hA[j];

      float grB = bf2f((ushortT)(((unsigned)giB_r[j >> 1]) >> ((j & 1) * 16)));
      float gzB = bf2f((ushortT)(((unsigned)giB_z[j >> 1]) >> ((j & 1) * 16)));
      float gnB = bf2f((ushortT)(((unsigned)giB_n[j >> 1]) >> ((j & 1) * 16)));
      float rr2 = sigf(grB + ghrB[j] + brB[j]);
      float zz2 = sigf(gzB + ghzB[j] + bzB[j]);
      float nn2 = tanhfast(gnB + binB[j] + rr2 * (ghnB[j] + bhnB[j]));
      float hv2 = nn2 + zz2 * (hB[j] - nn2);
      hB[j] = valid ? hv2 : hB[j];
    }
    if (valid && nflat < K) {
      *(float4v*)(out + (size_t)mcur * 256 + cA) = hA;
      *(float4v*)(out + (size_t)mcur * 256 + cB) = hB;
    }
    {
      ushort4v p0, p1;
#pragma unroll
      for (int j = 0; j < 4; ++j) { p0[j] = f2bf(hA[j]); p1[j] = f2bf(hB[j]); }
      *(ushort4v*)(hbf + bB * 264 + cA) = p0;
      *(ushort4v*)(hbf + bB * 264 + cB) = p1;
    }
    // issue next-step gi loads (vmem; rides across barrier, consumed next [B])
    {
      const ushortT* gp = gib + (size_t)max(pnext, 0) * 768;
      giA_r = *(const int2v*)(gp + cA);       giB_r = *(const int2v*)(gp + cB);
      giA_z = *(const int2v*)(gp + 256 + cA); giB_z = *(const int2v*)(gp + 256 + cB);
      giA_n = *(const int2v*)(gp + 512 + cA); giB_n = *(const int2v*)(gp + 512 + cB);
    }
    pcur = pnext; mcur = mnext;
    bar_lds();
  }

  // h_last
  *(float4v*)(out + HLAST_OFF + (size_t)bg * 256 + cA) = hA;
  *(float4v*)(out + HLAST_OFF + (size_t)bg * 256 + cB) = hB;
}

extern "C" void kernel_launch(void* const* d_in, const int* in_sizes, int n_in,
                              void* d_out, int out_size, void* d_ws, size_t ws_size,
                              hipStream_t stream) {
  const float* x = (const float*)d_in[0];
  const float* h0 = (const float*)d_in[1];
  const int* mask = (const int*)d_in[2];
  const float* Wih = (const float*)d_in[3];
  const float* Whh = (const float*)d_in[4];
  const float* bih = (const float*)d_in[5];
  const float* bhh = (const float*)d_in[6];
  float* out = (float*)d_out;
  int* wsi = (int*)d_ws;

  hipMemsetAsync(d_out, 0, (size_t)out_size * 4, stream);  // unmasked / padded positions emit 0

  k_prep<<<1, 512, 0, stream>>>(mask, wsi);
  k_build<<<512, 256, 0, stream>>>(mask, wsi);
  k_wcvt<<<384, 256, 0, stream>>>(Wih, Whh, wsi);
  k_gemm<<<dim3(1024, 6), 256, 0, stream>>>(x, wsi);
  k_rec<<<16, 512, 0, stream>>>(bih, bhh, h0, wsi, out);
}